// Round 8
// baseline (421.686 us; speedup 1.0000x reference)
//
#include <hip/hip_runtime.h>
#include <hip/hip_bf16.h>

// HCNet: L=4 hyper-connection blocks, N=4, D=2048, B*T=4096 tokens.
// R8: fused_dw stats computed on the MATRIX pipe: per token one 16x16x32
// MFMA chain, A-rows=[H0..H3,h2], B-cols=[gwm,gwr0-3,gwb0-3,ones,h2,H0..H3]
// -> all 43 reduction scalars in one shot (no wred). Coefficients via R6's
// verified cross-term algebra; apply = R6 folded form. gemm/width0/depth_last
// unchanged from R7.

#define DD 2048
#define NN 4
#define LL 4
#define NTOK 4096
#define EPSF 1e-5f

typedef __attribute__((ext_vector_type(8))) short bf16x8;
typedef __attribute__((ext_vector_type(4))) float f32x4;
typedef __attribute__((ext_vector_type(2))) float f32x2;

__device__ __forceinline__ float bf2f(short u) {
  union { unsigned int i; float f; } v;
  v.i = ((unsigned int)(unsigned short)u) << 16;
  return v.f;
}
__device__ __forceinline__ short f2bf(float f) {
  __hip_bfloat16 h = __float2bfloat16(f);
  short s;
  __builtin_memcpy(&s, &h, 2);
  return s;
}
__device__ __forceinline__ float wred(float v) {
#pragma unroll
  for (int off = 32; off > 0; off >>= 1) v += __shfl_xor(v, off, 64);
  return v;
}
__device__ __forceinline__ void ld16(const void* g, void* l) {
  __builtin_amdgcn_global_load_lds(
      (const __attribute__((address_space(1))) void*)g,
      (__attribute__((address_space(3))) void*)l, 16, 0, 0);
}

// ---------------- prep: gamma-scaled bf16 tables + beta/gamma ratio ---------
__global__ __launch_bounds__(256) void prep_pack(
    const float* __restrict__ W_m, const float* __restrict__ W_r,
    const float* __restrict__ W_b, const float* __restrict__ dyn_gamma,
    const float* __restrict__ norm_gamma, const float* __restrict__ norm_beta,
    short* __restrict__ gwm, short* __restrict__ gwr, short* __restrict__ gwb,
    float* __restrict__ rb) {
  const int i = blockIdx.x * 256 + threadIdx.x;  // over L*D = 8192
  const float g = dyn_gamma[i];
  gwm[i] = f2bf(g * W_m[i]);
  f32x4 r = *(const f32x4*)(W_r + (size_t)i * 4);
  f32x4 b = *(const f32x4*)(W_b + (size_t)i * 4);
  short ro[4], bo[4];
#pragma unroll
  for (int k = 0; k < 4; k++) { ro[k] = f2bf(g * r[k]); bo[k] = f2bf(g * b[k]); }
  *(unsigned long long*)(gwr + (size_t)i * 4) = *(unsigned long long*)ro;
  *(unsigned long long*)(gwb + (size_t)i * 4) = *(unsigned long long*)bo;
  rb[i] = norm_beta[i] / norm_gamma[i];
}

// ------- build MFMA B-operand tables (fragment layout) + zero stub ----------
// mtab[blk] (blk=0..2): B-cols [gwm(nb),gwr(nb)0-3,gwb(blk)0-3,ones,0...]
// entry for (kt,lane): value[j] = Bcol[lane&15][k = kt*32 + (lane>>4)*8 + j]
__global__ __launch_bounds__(256) void prep_mtab(
    const short* __restrict__ gwm, const short* __restrict__ gwr,
    const short* __restrict__ gwb, short* __restrict__ mtab,
    float* __restrict__ zerob) {
  const int blk = blockIdx.y;                       // 0..2
  const int kt = blockIdx.x * 4 + (threadIdx.x >> 6);  // 0..63
  const int lane = threadIdx.x & 63;
  const int col = lane & 15, kg = lane >> 4;
  const int k0 = kt * 32 + kg * 8;
  const int nb = blk + 1;
  short v[8];
#pragma unroll
  for (int j = 0; j < 8; j++) {
    const int k = k0 + j;
    short x = 0;
    if (col == 0) x = gwm[nb * DD + k];
    else if (col <= 4) x = gwr[((size_t)nb * DD + k) * 4 + (col - 1)];
    else if (col <= 8) x = gwb[((size_t)blk * DD + k) * 4 + (col - 5)];
    else if (col == 9) x = (short)0x3F80;  // bf16 1.0
    v[j] = x;
  }
  *(bf16x8*)(mtab + (size_t)blk * 32768 + (size_t)(kt * 64 + lane) * 8) =
      *(bf16x8*)v;
  if (blk == 0 && kt == 0 && lane == 0) {
    f32x4 z = {};
    *(f32x4*)zerob = z;
  }
}

// ---------------- token-independent sums S0w[l][5], T0d[l][4] ---------------
__global__ __launch_bounds__(64) void prep_sums(
    const float* __restrict__ W_m, const float* __restrict__ W_r,
    const float* __restrict__ W_b, const float* __restrict__ dyn_gamma,
    float* __restrict__ S0w, float* __restrict__ T0d) {
  const int l = blockIdx.x;
  const int lane = threadIdx.x;
  float s[5] = {0, 0, 0, 0, 0}, t[4] = {0, 0, 0, 0};
  for (int d = lane; d < DD; d += 64) {
    const float g = dyn_gamma[l * DD + d];
    s[0] += g * W_m[l * DD + d];
    f32x4 r = *(const f32x4*)(W_r + ((size_t)l * DD + d) * 4);
    f32x4 b = *(const f32x4*)(W_b + ((size_t)l * DD + d) * 4);
#pragma unroll
    for (int m = 0; m < 4; m++) { s[1 + m] += g * r[m]; t[m] += g * b[m]; }
  }
#pragma unroll
  for (int m = 0; m < 5; m++) s[m] = wred(s[m]);
#pragma unroll
  for (int n = 0; n < 4; n++) t[n] = wred(t[n]);
  if (lane == 0) {
#pragma unroll
    for (int m = 0; m < 5; m++) S0w[l * 5 + m] = s[m];
#pragma unroll
    for (int n = 0; n < 4; n++) T0d[l * 4 + n] = t[n];
  }
}

// ------- transpose Wblk[l][d][e] (f32) -> Wt[l][e][d] = norm_g[d]*W (bf16) --
__global__ __launch_bounds__(256) void transpose_wblk(
    const float* __restrict__ W, const float* __restrict__ norm_gamma,
    short* __restrict__ Wt) {
  __shared__ float tile[64][65];
  const int blk = blockIdx.z;
  const int c0 = blockIdx.x * 64;
  const int r0 = blockIdx.y * 64;
  const float* Ws = W + (size_t)blk * DD * DD;
  short* Wd = Wt + (size_t)blk * DD * DD;
  const int tx = threadIdx.x & 63, ty = threadIdx.x >> 6;
#pragma unroll
  for (int r = 0; r < 16; r++) {
    const int row = ty + r * 4;
    tile[row][tx] = Ws[(size_t)(r0 + row) * DD + c0 + tx];
  }
  const float gsc = norm_gamma[blk * DD + r0 + tx];
  __syncthreads();
#pragma unroll
  for (int r = 0; r < 16; r++) {
    const int row = ty + r * 4;
    Wd[(size_t)(c0 + row) * DD + r0 + tx] = f2bf(tile[tx][row] * gsc);
  }
}

// ---------------- row sums of Wt': E1 = sum_d Wt', E0 = sum_d rb*Wt' + bias -
__global__ __launch_bounds__(256) void row_sums(
    const short* __restrict__ Wt, const float* __restrict__ rb,
    const float* __restrict__ bblk, float* __restrict__ E0,
    float* __restrict__ E1) {
  const int l = blockIdx.y;
  const int e = blockIdx.x * 4 + (threadIdx.x >> 6);
  const int lane = threadIdx.x & 63;
  const short* row = Wt + ((size_t)l * DD + e) * DD;
  const float* rbl = rb + l * DD;
  float s1 = 0.f, s0 = 0.f;
#pragma unroll
  for (int it = 0; it < 4; it++) {
    const int d0 = lane * 8 + it * 512;
    bf16x8 w = *(const bf16x8*)(row + d0);
    f32x4 r0 = *(const f32x4*)(rbl + d0), r1 = *(const f32x4*)(rbl + d0 + 4);
#pragma unroll
    for (int q = 0; q < 8; q++) {
      const float wq = bf2f(w[q]);
      s1 += wq;
      s0 += wq * ((q < 4) ? r0[q] : r1[q - 4]);
    }
  }
  s1 = wred(s1); s0 = wred(s0);
  if (lane == 0) {
    E1[l * DD + e] = s1;
    E0[l * DD + e] = s0 + bblk[l * DD + e];
  }
}

// ---------------- width connections, block 0 (reads x f32) ------------------
__global__ __launch_bounds__(256) void width0_kernel(
    const float* __restrict__ x, short* __restrict__ Hst,
    short* __restrict__ hout, f32x2* __restrict__ tst,
    const float* __restrict__ A_m, const float* __restrict__ A_r,
    const short* __restrict__ gwm, const short* __restrict__ gwr,
    const float* __restrict__ s_a, const float* __restrict__ S0w) {
  const int wave = threadIdx.x >> 6;
  const int lane = threadIdx.x & 63;
  const int tok = blockIdx.x * 4 + wave;
  const int blk = 0;
  const short* wm = gwm + blk * DD;
  const short* wr = gwr + (size_t)blk * DD * 4;

  bf16x8 hreg[4];  // all N rows identical at block 0
  const float* xr = x + (size_t)tok * DD;
#pragma unroll
  for (int j = 0; j < 4; j++) {
    const int d0 = lane * 8 + j * 512;
    f32x4 a = *(const f32x4*)(xr + d0);
    f32x4 b = *(const f32x4*)(xr + d0 + 4);
    bf16x8 p;
#pragma unroll
    for (int q = 0; q < 4; q++) { p[q] = f2bf(a[q]); p[4 + q] = f2bf(b[q]); }
    hreg[j] = p;
  }

  float sH = 0, sH2 = 0, S1[5] = {0, 0, 0, 0, 0};
#pragma unroll
  for (int j = 0; j < 4; j++) {
    const int d0 = lane * 8 + j * 512;
    bf16x8 mv = *(const bf16x8*)(wm + d0);
    bf16x8 wv[4];
#pragma unroll
    for (int p = 0; p < 4; p++)
      wv[p] = *(const bf16x8*)(wr + (size_t)(d0 + 2 * p) * 4);
#pragma unroll
    for (int q = 0; q < 8; q++) {
      const float hv = bf2f(hreg[j][q]);
      sH += hv; sH2 += hv * hv;
      S1[0] += hv * bf2f(mv[q]);
#pragma unroll
      for (int m = 0; m < 4; m++)
        S1[1 + m] += hv * bf2f(wv[q >> 1][(q & 1) * 4 + m]);
    }
  }
  sH = wred(sH); sH2 = wred(sH2);
#pragma unroll
  for (int m = 0; m < 5; m++) S1[m] = wred(S1[m]);

  const float sa = s_a[blk];
  const float mu0 = sH * (1.f / DD);
  const float inv0 = rsqrtf(sH2 * (1.f / DD) - mu0 * mu0 + EPSF);
  float amSum = 0.f, arCol[NN] = {0, 0, 0, 0};
  {
    const float t0 = tanhf(inv0 * (S1[0] - mu0 * S0w[blk * 5 + 0]));
    float tm[NN];
#pragma unroll
    for (int m = 0; m < NN; m++)
      tm[m] = tanhf(inv0 * (S1[1 + m] - mu0 * S0w[blk * 5 + 1 + m]));
#pragma unroll
    for (int n = 0; n < NN; n++) {
      amSum += A_m[blk * NN + n] + sa * t0;
#pragma unroll
      for (int m = 0; m < NN; m++)
        arCol[m] += A_r[blk * NN * NN + n * NN + m] + sa * tm[m];
    }
  }

  short* Ho = Hst + (size_t)tok * NN * DD;
  short* hw = hout + (size_t)tok * DD;
  float sh = 0.f, sh2 = 0.f;
#pragma unroll
  for (int j = 0; j < 4; j++) {
    const int d0 = lane * 8 + j * 512;
    bf16x8 outp[NN], ho;
#pragma unroll
    for (int q = 0; q < 8; q++) {
      const float hv = bf2f(hreg[j][q]);
      const float a0 = hv * amSum;
      sh += a0; sh2 += a0 * a0;
      ho[q] = f2bf(a0);
#pragma unroll
      for (int m = 0; m < NN; m++) outp[m][q] = f2bf(hv * arCol[m]);
    }
    *(bf16x8*)(hw + d0) = ho;
#pragma unroll
    for (int m = 0; m < NN; m++) *(bf16x8*)(Ho + m * DD + d0) = outp[m];
  }
  sh = wred(sh); sh2 = wred(sh2);
  if (lane == 0) {
    const float mu = sh * (1.f / DD);
    const float inv = rsqrtf(sh2 * (1.f / DD) - mu * mu + EPSF);
    f32x2 t; t[0] = inv; t[1] = mu * inv;
    tst[tok] = t;
  }
}

// ---------------- block GEMM: h2 = LN-folded(h @ Wt') -----------------------
__global__ __launch_bounds__(512) void gemm_kernel(
    const short* __restrict__ A, const short* __restrict__ Bt,
    const f32x2* __restrict__ tst, const float* __restrict__ E0,
    const float* __restrict__ E1, short* __restrict__ C) {
  __shared__ short lA[2][128 * 64];
  __shared__ short lB[2][128 * 64];
  const int tid = threadIdx.x;
  const int lane = tid & 63;
  const int wave = tid >> 6;   // 0..7
  const int bid = blockIdx.x;
  const int wg = (bid & 7) * 64 + (bid >> 3);
  const int m0 = (wg & 31) * 128, n0 = (wg >> 5) * 128;
  const int wm = wave >> 2;    // 0..1: 64-row group
  const int wn = wave & 3;     // 0..3: 32-col group

  f32x4 acc[4][2] = {};

#define STAGE(buf, kt)                                                        \
  {                                                                           \
    const int k0 = (kt) * 64;                                                 \
    _Pragma("unroll") for (int c = 0; c < 2; c++) {                           \
      const int idx = c * 512 + tid;                                          \
      const int row = idx >> 3;                                               \
      const int colsw = (((idx & 7) ^ (row & 7)) * 8);                        \
      ld16(A + (size_t)(m0 + row) * DD + k0 + colsw,                          \
           (char*)&lA[buf][0] + idx * 16);                                    \
      ld16(Bt + (size_t)(n0 + row) * DD + k0 + colsw,                         \
           (char*)&lB[buf][0] + idx * 16);                                    \
    }                                                                         \
  }

  STAGE(0, 0);
  __syncthreads();

  for (int kt = 0; kt < 32; ++kt) {
    const int cur = kt & 1;
    if (kt < 31) STAGE(cur ^ 1, kt + 1);
    const char* bufA = (const char*)&lA[cur][0];
    const char* bufB = (const char*)&lB[cur][0];
#pragma unroll
    for (int kk = 0; kk < 2; ++kk) {
      const int gsw = (kk * 64 + (lane >> 4) * 16) ^ ((lane & 7) << 4);
      bf16x8 af[4], bfr[2];
#pragma unroll
      for (int m = 0; m < 4; m++) {
        const int r = wm * 64 + m * 16 + (lane & 15);
        af[m] = *(const bf16x8*)(bufA + r * 128 + gsw);
      }
#pragma unroll
      for (int n = 0; n < 2; n++) {
        const int r = wn * 32 + n * 16 + (lane & 15);
        bfr[n] = *(const bf16x8*)(bufB + r * 128 + gsw);
      }
#pragma unroll
      for (int m = 0; m < 4; m++)
#pragma unroll
        for (int n = 0; n < 2; n++)
          acc[m][n] = __builtin_amdgcn_mfma_f32_16x16x32_bf16(
              af[m], bfr[n], acc[m][n], 0, 0, 0);
    }
    __syncthreads();
  }
#undef STAGE

  float e0c[2], e1c[2];
  int cols[2];
#pragma unroll
  for (int n = 0; n < 2; n++) {
    cols[n] = n0 + wn * 32 + n * 16 + (lane & 15);
    e0c[n] = E0[cols[n]];
    e1c[n] = E1[cols[n]];
  }
#pragma unroll
  for (int m = 0; m < 4; m++) {
    const int rbase = m0 + wm * 64 + m * 16 + ((lane >> 4) << 2);
#pragma unroll
    for (int j = 0; j < 4; j++) {
      const int row = rbase + j;
      const f32x2 iv = tst[row];
#pragma unroll
      for (int n = 0; n < 2; n++)
        C[(size_t)row * DD + cols[n]] =
            f2bf(iv[0] * acc[m][n][j] - iv[1] * e1c[n] + e0c[n]);
    }
  }
}

// ---------------- fused depth(blk) + width(blk+1): MFMA stats ---------------
__global__ __launch_bounds__(256) void fused_dw(
    const short* __restrict__ h2, short* __restrict__ Hst,
    short* __restrict__ hout, f32x2* __restrict__ tst,
    const float* __restrict__ Bp, const float* __restrict__ s_b,
    const float* __restrict__ A_m, const float* __restrict__ A_r,
    const float* __restrict__ s_a, const float* __restrict__ S0w,
    const float* __restrict__ T0d, const short* __restrict__ mtab,
    const char* __restrict__ zerob, int blk) {
  const int wave = threadIdx.x >> 6;
  const int lane = threadIdx.x & 63;
  const int tok = blockIdx.x * 4 + wave;
  const int nblk = blk + 1;
  const short* Hbase = Hst + (size_t)tok * NN * DD;
  const short* h2b = h2 + (size_t)tok * DD;
  const int col = lane & 15, kg = lane >> 4;

  // apply-phase h2 preload (issue early)
  bf16x8 h2r[4];
#pragma unroll
  for (int j = 0; j < 4; j++)
    h2r[j] = *(const bf16x8*)(h2b + lane * 8 + j * 512);

  // ---- MFMA stats: A rows [H0..H3,h2,0..], B cols per mtab + runtime ----
  const char* ap; int astp;
  if (col < 4) { ap = (const char*)(Hbase + col * DD) + kg * 16; astp = 64; }
  else if (col == 4) { ap = (const char*)h2b + kg * 16; astp = 64; }
  else { ap = zerob; astp = 0; }
  const char* bp; int bstp;
  if (col == 10) { bp = (const char*)h2b + kg * 16; bstp = 64; }
  else if (col >= 11 && col <= 14) {
    bp = (const char*)(Hbase + (col - 11) * DD) + kg * 16; bstp = 64;
  } else {
    bp = (const char*)mtab + (size_t)blk * 65536 + lane * 16; bstp = 1024;
  }

  f32x4 ac0 = {}, ac1 = {}, ac2 = {}, ac3 = {};
  for (int kt = 0; kt < 64; kt += 4) {
    bf16x8 a0 = *(const bf16x8*)(ap + (kt + 0) * astp);
    bf16x8 b0 = *(const bf16x8*)(bp + (kt + 0) * bstp);
    bf16x8 a1 = *(const bf16x8*)(ap + (kt + 1) * astp);
    bf16x8 b1 = *(const bf16x8*)(bp + (kt + 1) * bstp);
    bf16x8 a2 = *(const bf16x8*)(ap + (kt + 2) * astp);
    bf16x8 b2 = *(const bf16x8*)(bp + (kt + 2) * bstp);
    bf16x8 a3 = *(const bf16x8*)(ap + (kt + 3) * astp);
    bf16x8 b3 = *(const bf16x8*)(bp + (kt + 3) * bstp);
    ac0 = __builtin_amdgcn_mfma_f32_16x16x32_bf16(a0, b0, ac0, 0, 0, 0);
    ac1 = __builtin_amdgcn_mfma_f32_16x16x32_bf16(a1, b1, ac1, 0, 0, 0);
    ac2 = __builtin_amdgcn_mfma_f32_16x16x32_bf16(a2, b2, ac2, 0, 0, 0);
    ac3 = __builtin_amdgcn_mfma_f32_16x16x32_bf16(a3, b3, ac3, 0, 0, 0);
  }
  f32x4 Dv = (ac0 + ac1) + (ac2 + ac3);

  // ---- extract stats (D layout: col=lane&15, row=(lane>>4)*4+reg) ----
  float U1[5], T1[4];
#pragma unroll
  for (int m = 0; m < 5; m++) U1[m] = __shfl(Dv[0], 16 + m, 64);
#pragma unroll
  for (int n = 0; n < NN; n++) T1[n] = __shfl(Dv[0], 21 + n, 64);
  const float s1 = __shfl(Dv[0], 25, 64);
  const float s2 = __shfl(Dv[0], 26, 64);
  float S1r[NN][5], sH[NN], Cx[NN], sHH[NN];
#pragma unroll
  for (int n = 0; n < NN; n++) {
    const float dn = Dv[n];
    sH[n] = __shfl(dn, 9, 64);
    Cx[n] = __shfl(dn, 10, 64);
    sHH[n] = __shfl(dn, 11 + n, 64);
#pragma unroll
    for (int m = 0; m < 5; m++) S1r[n][m] = __shfl(dn, m, 64);
  }

  // ---- depth coefficients ----
  float Bv[NN];
  {
    const float mu2 = s1 * (1.f / DD);
    const float inv2 = rsqrtf(s2 * (1.f / DD) - mu2 * mu2 + EPSF);
    const float sb = s_b[blk];
#pragma unroll
    for (int n = 0; n < NN; n++)
      Bv[n] = Bp[blk * NN + n] +
              sb * tanhf(inv2 * (T1[n] - mu2 * T0d[blk * NN + n]));
  }

  // ---- width coefficients via cross-term expansion (R6, verified) ----
  const float sa = s_a[nblk];
  float Am[NN], Ar[NN][NN];
#pragma unroll
  for (int n = 0; n < NN; n++) {
    const float sHp = sH[n] + Bv[n] * s1;
    const float sH2p = sHH[n] + 2.f * Bv[n] * Cx[n] + Bv[n] * Bv[n] * s2;
    const float mu = sHp * (1.f / DD);
    const float inv = rsqrtf(sH2p * (1.f / DD) - mu * mu + EPSF);
    const float S10 = S1r[n][0] + Bv[n] * U1[0];
    Am[n] = A_m[nblk * NN + n] +
            sa * tanhf(inv * (S10 - mu * S0w[nblk * 5 + 0]));
#pragma unroll
    for (int m = 0; m < NN; m++) {
      const float S1m = S1r[n][1 + m] + Bv[n] * U1[1 + m];
      Ar[n][m] = A_r[nblk * NN * NN + n * NN + m] +
                 sa * tanhf(inv * (S1m - mu * S0w[nblk * 5 + 1 + m]));
    }
  }
  float ca = 0.f, cr[NN] = {0, 0, 0, 0};
#pragma unroll
  for (int n = 0; n < NN; n++) {
    ca += Bv[n] * Am[n];
#pragma unroll
    for (int m = 0; m < NN; m++) cr[m] += Bv[n] * Ar[n][m];
  }

  // ---- apply (H streamed per-j, H' folded into coefficients) ----
  short* HoW = Hst + (size_t)tok * NN * DD;
  short* hw = hout + (size_t)tok * DD;
  float sh = 0.f, sh2 = 0.f;
#pragma unroll
  for (int j = 0; j < 4; j++) {
    const int d0 = lane * 8 + j * 512;
    bf16x8 hold[NN];
#pragma unroll
    for (int n = 0; n < NN; n++) hold[n] = *(const bf16x8*)(Hbase + n * DD + d0);
    bf16x8 outp[NN], ho;
#pragma unroll
    for (int q = 0; q < 8; q++) {
      const float hv2 = bf2f(h2r[j][q]);
      float a0 = hv2 * ca;
      float am0 = hv2 * cr[0], am1 = hv2 * cr[1];
      float am2 = hv2 * cr[2], am3 = hv2 * cr[3];
#pragma unroll
      for (int n = 0; n < NN; n++) {
        const float hvn = bf2f(hold[n][q]);
        a0 += hvn * Am[n];
        am0 += hvn * Ar[n][0];
        am1 += hvn * Ar[n][1];
        am2 += hvn * Ar[n][2];
        am3 += hvn * Ar[n][3];
      }
      sh += a0; sh2 += a0 * a0;
      ho[q] = f2bf(a0);
      outp[0][q] = f2bf(am0); outp[1][q] = f2bf(am1);
      outp[2][q] = f2bf(am2); outp[3][q] = f2bf(am3);
    }
    *(bf16x8*)(hw + d0) = ho;
#pragma unroll
    for (int m = 0; m < NN; m++) *(bf16x8*)(HoW + m * DD + d0) = outp[m];
  }
  sh = wred(sh); sh2 = wred(sh2);
  if (lane == 0) {
    const float mu = sh * (1.f / DD);
    const float inv = rsqrtf(sh2 * (1.f / DD) - mu * mu + EPSF);
    f32x2 t; t[0] = inv; t[1] = mu * inv;
    tst[tok] = t;
  }
}

// ---------------- final depth (block 3) + output sum ------------------------
__global__ __launch_bounds__(256) void depth_last(
    const short* __restrict__ h2, const short* __restrict__ Hst,
    float* __restrict__ out, const float* __restrict__ Bp,
    const short* __restrict__ gwb, const float* __restrict__ s_b,
    const float* __restrict__ T0d, int blk) {
  const int wave = threadIdx.x >> 6;
  const int lane = threadIdx.x & 63;
  const int tok = blockIdx.x * 4 + wave;
  const short* hr = h2 + (size_t)tok * DD;
  const short* wb = gwb + (size_t)blk * DD * 4;

  bf16x8 h2r[4];
  float s1 = 0.f, s2 = 0.f, T1[NN] = {0, 0, 0, 0};
#pragma unroll
  for (int j = 0; j < 4; j++) {
    const int d0 = lane * 8 + j * 512;
    h2r[j] = *(const bf16x8*)(hr + d0);
    bf16x8 wv[4];
#pragma unroll
    for (int p = 0; p < 4; p++)
      wv[p] = *(const bf16x8*)(wb + (size_t)(d0 + 2 * p) * 4);
#pragma unroll
    for (int q = 0; q < 8; q++) {
      const float hv = bf2f(h2r[j][q]);
      s1 += hv; s2 += hv * hv;
#pragma unroll
      for (int n = 0; n < NN; n++)
        T1[n] += hv * bf2f(wv[q >> 1][(q & 1) * 4 + n]);
    }
  }
  s1 = wred(s1); s2 = wred(s2);
#pragma unroll
  for (int n = 0; n < NN; n++) T1[n] = wred(T1[n]);
  const float mu = s1 * (1.f / DD);
  const float inv = rsqrtf(s2 * (1.f / DD) - mu * mu + EPSF);
  const float sb = s_b[blk];
  float bsum = 0.f;
#pragma unroll
  for (int n = 0; n < NN; n++)
    bsum += Bp[blk * NN + n] + sb * tanhf(inv * (T1[n] - mu * T0d[blk * NN + n]));

  const short* Ho = Hst + (size_t)tok * NN * DD;
  float* orow = out + (size_t)tok * DD;
#pragma unroll
  for (int j = 0; j < 4; j++) {
    const int d0 = lane * 8 + j * 512;
    bf16x8 hrow[NN];
#pragma unroll
    for (int n = 0; n < NN; n++) hrow[n] = *(const bf16x8*)(Ho + n * DD + d0);
    f32x4 o0, o1;
#pragma unroll
    for (int q = 0; q < 8; q++) {
      const float hv = bf2f(h2r[j][q]);
      float s = hv * bsum;
#pragma unroll
      for (int n = 0; n < NN; n++) s += bf2f(hrow[n][q]);
      if (q < 4) o0[q] = s; else o1[q - 4] = s;
    }
    *(f32x4*)(orow + d0) = o0;
    *(f32x4*)(orow + d0 + 4) = o1;
  }
}

extern "C" void kernel_launch(void* const* d_in, const int* in_sizes, int n_in,
                              void* d_out, int out_size, void* d_ws,
                              size_t ws_size, hipStream_t stream) {
  const float* x = (const float*)d_in[0];
  const float* A_m = (const float*)d_in[1];
  const float* A_r = (const float*)d_in[2];
  const float* Bp = (const float*)d_in[3];
  const float* W_m = (const float*)d_in[4];
  const float* W_r = (const float*)d_in[5];
  const float* W_b = (const float*)d_in[6];
  const float* s_a = (const float*)d_in[7];
  const float* s_b = (const float*)d_in[8];
  const float* dyn_gamma = (const float*)d_in[9];
  const float* norm_gamma = (const float*)d_in[10];
  const float* norm_beta = (const float*)d_in[11];
  const float* Wblk = (const float*)d_in[12];
  const float* bblk = (const float*)d_in[13];
  float* out = (float*)d_out;

  char* ws = (char*)d_ws;
  short* Hst = (short*)(ws);                      // [0, 64 MiB)
  short* hbuf = (short*)(ws + 67108864);          // [64, 80) unnormalized h
  short* h2 = (short*)(ws + 83886080);            // [80, 96)
  char* aux = ws + 100663296;                     // [96 MiB, ...)
  short* gwm = (short*)(aux);                     // 16 KiB
  short* gwr = (short*)(aux + 16384);             // 64 KiB
  short* gwb = (short*)(aux + 16384 + 65536);     // 64 KiB
  float* rb = (float*)(aux + 16384 + 131072);     // 32 KiB
  float* S0w = (float*)(aux + 16384 + 131072 + 32768);
  float* T0d = (float*)(aux + 16384 + 131072 + 32768 + 128);
  f32x2* tst = (f32x2*)(aux + 16384 + 131072 + 32768 + 256);  // 32 KiB
  float* E0 = (float*)(aux + 16384 + 131072 + 32768 + 256 + 32768);  // 32 KiB
  float* E1 = E0 + LL * DD;                                          // 32 KiB
  float* zerob = (float*)(aux + 294912);          // 16 B zero stub
  short* mtab = (short*)(aux + 524288);           // 3 x 64 KiB fragment tables
  // Wt lives in d_out: recomputed every call, overwritten by depth_last
  short* Wt = (short*)d_out;

  dim3 tb(256);
  prep_pack<<<32, tb, 0, stream>>>(W_m, W_r, W_b, dyn_gamma, norm_gamma,
                                   norm_beta, gwm, gwr, gwb, rb);
  prep_mtab<<<dim3(16, 3), tb, 0, stream>>>(gwm, gwr, gwb, mtab, zerob);
  prep_sums<<<4, dim3(64), 0, stream>>>(W_m, W_r, W_b, dyn_gamma, S0w, T0d);
  transpose_wblk<<<dim3(32, 32, 4), tb, 0, stream>>>(Wblk, norm_gamma, Wt);
  row_sums<<<dim3(512, 4), tb, 0, stream>>>(Wt, rb, bblk, E0, E1);
  width0_kernel<<<1024, tb, 0, stream>>>(x, Hst, hbuf, tst, A_m, A_r, gwm,
                                         gwr, s_a, S0w);
  for (int i = 0; i < LL; i++) {
    gemm_kernel<<<512, dim3(512), 0, stream>>>(
        hbuf, Wt + (size_t)i * DD * DD, tst, E0 + i * DD, E1 + i * DD, h2);
    if (i < LL - 1)
      fused_dw<<<1024, tb, 0, stream>>>(h2, Hst, hbuf, tst, Bp, s_b, A_m, A_r,
                                        s_a, S0w, T0d, mtab, (const char*)zerob,
                                        i);
    else
      depth_last<<<1024, tb, 0, stream>>>(h2, Hst, out, Bp, gwb, s_b, T0d, i);
  }
}

// Round 9
// 326.737 us; speedup vs baseline: 1.2906x; 1.2906x over previous
//
#include <hip/hip_runtime.h>
#include <hip/hip_bf16.h>

// HCNet: L=4 hyper-connection blocks, N=4, D=2048, B*T=4096 tokens.
// R9: basis decomposition. H rows stay in span{x, h2^0..h2^2}; track 4xK
// coefficient matrix C per token instead of materializing H. Stats via
// Gram matrix G, ones-sums o, and store-forwarded table dots P. fused_dw
// = dots on new h2 + tiny coefficient algebra + hnorm combo write.

#define DD 2048
#define NN 4
#define LL 4
#define NTOK 4096
#define EPSF 1e-5f
#define STS 80  // ST row stride (floats)

typedef __attribute__((ext_vector_type(8))) short bf16x8;
typedef __attribute__((ext_vector_type(4))) float f32x4;
typedef __attribute__((ext_vector_type(2))) float f32x2;

__device__ __forceinline__ float bf2f(short u) {
  union { unsigned int i; float f; } v;
  v.i = ((unsigned int)(unsigned short)u) << 16;
  return v.f;
}
__device__ __forceinline__ short f2bf(float f) {
  __hip_bfloat16 h = __float2bfloat16(f);
  short s;
  __builtin_memcpy(&s, &h, 2);
  return s;
}
__device__ __forceinline__ float wred(float v) {
#pragma unroll
  for (int off = 32; off > 0; off >>= 1) v += __shfl_xor(v, off, 64);
  return v;
}
__device__ __forceinline__ void ld16(const void* g, void* l) {
  __builtin_amdgcn_global_load_lds(
      (const __attribute__((address_space(1))) void*)g,
      (__attribute__((address_space(3))) void*)l, 16, 0, 0);
}
// ST float offsets: o[0..3] at 0..3; G[k][j] at 4+k*4+j (k,j<=3);
// P[k][l] (5 floats) at pofs(k,l)
__host__ __device__ constexpr int pofs(int k, int l) {
  return k == 0 ? 20 + l * 5
       : k == 1 ? 40 + (l - 1) * 5
       : k == 2 ? 55 + (l - 2) * 5
                : 65;
}

// ---------------- prep: gamma-scaled bf16 tables + beta/gamma ratio ---------
__global__ __launch_bounds__(256) void prep_pack(
    const float* __restrict__ W_m, const float* __restrict__ W_r,
    const float* __restrict__ W_b, const float* __restrict__ dyn_gamma,
    const float* __restrict__ norm_gamma, const float* __restrict__ norm_beta,
    short* __restrict__ gwm, short* __restrict__ gwr, short* __restrict__ gwb,
    float* __restrict__ rb) {
  const int i = blockIdx.x * 256 + threadIdx.x;  // over L*D = 8192
  const float g = dyn_gamma[i];
  gwm[i] = f2bf(g * W_m[i]);
  f32x4 r = *(const f32x4*)(W_r + (size_t)i * 4);
  f32x4 b = *(const f32x4*)(W_b + (size_t)i * 4);
  short ro[4], bo[4];
#pragma unroll
  for (int k = 0; k < 4; k++) { ro[k] = f2bf(g * r[k]); bo[k] = f2bf(g * b[k]); }
  *(unsigned long long*)(gwr + (size_t)i * 4) = *(unsigned long long*)ro;
  *(unsigned long long*)(gwb + (size_t)i * 4) = *(unsigned long long*)bo;
  rb[i] = norm_beta[i] / norm_gamma[i];
}

// ---------------- token-independent sums S0w[l][5], T0d[l][4] ---------------
__global__ __launch_bounds__(64) void prep_sums(
    const float* __restrict__ W_m, const float* __restrict__ W_r,
    const float* __restrict__ W_b, const float* __restrict__ dyn_gamma,
    float* __restrict__ S0w, float* __restrict__ T0d) {
  const int l = blockIdx.x;
  const int lane = threadIdx.x;
  float s[5] = {0, 0, 0, 0, 0}, t[4] = {0, 0, 0, 0};
  for (int d = lane; d < DD; d += 64) {
    const float g = dyn_gamma[l * DD + d];
    s[0] += g * W_m[l * DD + d];
    f32x4 r = *(const f32x4*)(W_r + ((size_t)l * DD + d) * 4);
    f32x4 b = *(const f32x4*)(W_b + ((size_t)l * DD + d) * 4);
#pragma unroll
    for (int m = 0; m < 4; m++) { s[1 + m] += g * r[m]; t[m] += g * b[m]; }
  }
#pragma unroll
  for (int m = 0; m < 5; m++) s[m] = wred(s[m]);
#pragma unroll
  for (int n = 0; n < 4; n++) t[n] = wred(t[n]);
  if (lane == 0) {
#pragma unroll
    for (int m = 0; m < 5; m++) S0w[l * 5 + m] = s[m];
#pragma unroll
    for (int n = 0; n < 4; n++) T0d[l * 4 + n] = t[n];
  }
}

// ------- transpose Wblk[l][d][e] (f32) -> Wt[l][e][d] = norm_g[d]*W (bf16) --
__global__ __launch_bounds__(256) void transpose_wblk(
    const float* __restrict__ W, const float* __restrict__ norm_gamma,
    short* __restrict__ Wt) {
  __shared__ float tile[64][65];
  const int blk = blockIdx.z;
  const int c0 = blockIdx.x * 64;
  const int r0 = blockIdx.y * 64;
  const float* Ws = W + (size_t)blk * DD * DD;
  short* Wd = Wt + (size_t)blk * DD * DD;
  const int tx = threadIdx.x & 63, ty = threadIdx.x >> 6;
#pragma unroll
  for (int r = 0; r < 16; r++) {
    const int row = ty + r * 4;
    tile[row][tx] = Ws[(size_t)(r0 + row) * DD + c0 + tx];
  }
  const float gsc = norm_gamma[blk * DD + r0 + tx];
  __syncthreads();
#pragma unroll
  for (int r = 0; r < 16; r++) {
    const int row = ty + r * 4;
    Wd[(size_t)(c0 + row) * DD + r0 + tx] = f2bf(tile[tx][row] * gsc);
  }
}

// ---------------- row sums of Wt': E1 = sum_d Wt', E0 = sum_d rb*Wt' + bias -
__global__ __launch_bounds__(256) void row_sums(
    const short* __restrict__ Wt, const float* __restrict__ rb,
    const float* __restrict__ bblk, float* __restrict__ E0,
    float* __restrict__ E1) {
  const int l = blockIdx.y;
  const int e = blockIdx.x * 4 + (threadIdx.x >> 6);
  const int lane = threadIdx.x & 63;
  const short* row = Wt + ((size_t)l * DD + e) * DD;
  const float* rbl = rb + l * DD;
  float s1 = 0.f, s0 = 0.f;
#pragma unroll
  for (int it = 0; it < 4; it++) {
    const int d0 = lane * 8 + it * 512;
    bf16x8 w = *(const bf16x8*)(row + d0);
    f32x4 r0 = *(const f32x4*)(rbl + d0), r1 = *(const f32x4*)(rbl + d0 + 4);
#pragma unroll
    for (int q = 0; q < 8; q++) {
      const float wq = bf2f(w[q]);
      s1 += wq;
      s0 += wq * ((q < 4) ? r0[q] : r1[q - 4]);
    }
  }
  s1 = wred(s1); s0 = wred(s0);
  if (lane == 0) {
    E1[l * DD + e] = s1;
    E0[l * DD + e] = s0 + bblk[l * DD + e];
  }
}

// ---------------- width0: x-dots + block-0 coefficients + hnorm -------------
__global__ __launch_bounds__(256) void width0_kernel(
    const float* __restrict__ x, short* __restrict__ b0,
    short* __restrict__ hout, f32x2* __restrict__ tst, float* __restrict__ Cc,
    float* __restrict__ ST, const float* __restrict__ A_m,
    const float* __restrict__ A_r, const short* __restrict__ gwm,
    const short* __restrict__ gwr, const float* __restrict__ s_a,
    const float* __restrict__ S0w) {
  const int wave = threadIdx.x >> 6;
  const int lane = threadIdx.x & 63;
  const int tok = blockIdx.x * 4 + wave;
  const float* xr = x + (size_t)tok * DD;
  short* b0t = b0 + (size_t)tok * DD;

  bf16x8 xb[4];
#pragma unroll
  for (int j = 0; j < 4; j++) {
    const int d0 = lane * 8 + j * 512;
    f32x4 a = *(const f32x4*)(xr + d0);
    f32x4 b = *(const f32x4*)(xr + d0 + 4);
    bf16x8 p;
#pragma unroll
    for (int q = 0; q < 4; q++) { p[q] = f2bf(a[q]); p[4 + q] = f2bf(b[q]); }
    xb[j] = p;
    *(bf16x8*)(b0t + d0) = p;
  }

  float o = 0.f, qq = 0.f, P0[4][5];
#pragma unroll
  for (int l = 0; l < 4; l++)
#pragma unroll
    for (int m = 0; m < 5; m++) P0[l][m] = 0.f;

#pragma unroll
  for (int j = 0; j < 4; j++) {
    const int d0 = lane * 8 + j * 512;
    bf16x8 wmv[4], wrv[4][4];
#pragma unroll
    for (int l = 0; l < 4; l++) {
      wmv[l] = *(const bf16x8*)(gwm + l * DD + d0);
#pragma unroll
      for (int p = 0; p < 4; p++)
        wrv[l][p] = *(const bf16x8*)(gwr + ((size_t)l * DD + d0 + 2 * p) * 4);
    }
#pragma unroll
    for (int q = 0; q < 8; q++) {
      const float hv = bf2f(xb[j][q]);
      o += hv; qq += hv * hv;
#pragma unroll
      for (int l = 0; l < 4; l++) {
        P0[l][0] += hv * bf2f(wmv[l][q]);
#pragma unroll
        for (int m = 0; m < 4; m++)
          P0[l][1 + m] += hv * bf2f(wrv[l][q >> 1][(q & 1) * 4 + m]);
      }
    }
  }
  o = wred(o); qq = wred(qq);
#pragma unroll
  for (int l = 0; l < 4; l++)
#pragma unroll
    for (int m = 0; m < 5; m++) P0[l][m] = wred(P0[l][m]);

  // block-0 width coefficients (all H rows = x)
  const float sa = s_a[0];
  const float mu = o * (1.f / DD);
  const float inv = rsqrtf(qq * (1.f / DD) - mu * mu + EPSF);
  const float t0 = tanhf(inv * (P0[0][0] - mu * S0w[0]));
  float tm[4];
#pragma unroll
  for (int m = 0; m < 4; m++)
    tm[m] = tanhf(inv * (P0[0][1 + m] - mu * S0w[1 + m]));
  float amSum = 0.f, arCol[4] = {0, 0, 0, 0};
#pragma unroll
  for (int n = 0; n < 4; n++) {
    amSum += A_m[n] + sa * t0;
#pragma unroll
    for (int m = 0; m < 4; m++) arCol[m] += A_r[n * 4 + m] + sa * tm[m];
  }

  if (lane == 0) {
    const float sh = amSum * o;
    const float sh2 = amSum * amSum * qq;
    const float mu2 = sh * (1.f / DD);
    const float inv2 = rsqrtf(sh2 * (1.f / DD) - mu2 * mu2 + EPSF);
    f32x2 t; t[0] = inv2; t[1] = mu2 * inv2;
    tst[tok] = t;
    float* STt = ST + (size_t)tok * STS;
    STt[0] = o;
    STt[4] = qq;  // G[0][0]
#pragma unroll
    for (int l = 0; l < 4; l++)
#pragma unroll
      for (int m = 0; m < 5; m++) STt[pofs(0, l) + m] = P0[l][m];
    float* Ct = Cc + (size_t)tok * 16;
#pragma unroll
    for (int n = 0; n < 4; n++) Ct[n * 4] = arCol[n];
  }

  short* hw = hout + (size_t)tok * DD;
#pragma unroll
  for (int j = 0; j < 4; j++) {
    const int d0 = lane * 8 + j * 512;
    bf16x8 ho;
#pragma unroll
    for (int q = 0; q < 8; q++) ho[q] = f2bf(amSum * bf2f(xb[j][q]));
    *(bf16x8*)(hw + d0) = ho;
  }
}

// ---------------- block GEMM: h2 = LN-folded(h @ Wt') -----------------------
__global__ __launch_bounds__(512) void gemm_kernel(
    const short* __restrict__ A, const short* __restrict__ Bt,
    const f32x2* __restrict__ tst, const float* __restrict__ E0,
    const float* __restrict__ E1, short* __restrict__ C) {
  __shared__ short lA[2][128 * 64];
  __shared__ short lB[2][128 * 64];
  const int tid = threadIdx.x;
  const int lane = tid & 63;
  const int wave = tid >> 6;
  const int bid = blockIdx.x;
  const int wg = (bid & 7) * 64 + (bid >> 3);
  const int m0 = (wg & 31) * 128, n0 = (wg >> 5) * 128;
  const int wm = wave >> 2;
  const int wn = wave & 3;

  f32x4 acc[4][2] = {};

#define STAGE(buf, kt)                                                        \
  {                                                                           \
    const int k0 = (kt) * 64;                                                 \
    _Pragma("unroll") for (int c = 0; c < 2; c++) {                           \
      const int idx = c * 512 + tid;                                          \
      const int row = idx >> 3;                                               \
      const int colsw = (((idx & 7) ^ (row & 7)) * 8);                        \
      ld16(A + (size_t)(m0 + row) * DD + k0 + colsw,                          \
           (char*)&lA[buf][0] + idx * 16);                                    \
      ld16(Bt + (size_t)(n0 + row) * DD + k0 + colsw,                         \
           (char*)&lB[buf][0] + idx * 16);                                    \
    }                                                                         \
  }

  STAGE(0, 0);
  __syncthreads();

  for (int kt = 0; kt < 32; ++kt) {
    const int cur = kt & 1;
    if (kt < 31) STAGE(cur ^ 1, kt + 1);
    const char* bufA = (const char*)&lA[cur][0];
    const char* bufB = (const char*)&lB[cur][0];
#pragma unroll
    for (int kk = 0; kk < 2; ++kk) {
      const int gsw = (kk * 64 + (lane >> 4) * 16) ^ ((lane & 7) << 4);
      bf16x8 af[4], bfr[2];
#pragma unroll
      for (int m = 0; m < 4; m++) {
        const int r = wm * 64 + m * 16 + (lane & 15);
        af[m] = *(const bf16x8*)(bufA + r * 128 + gsw);
      }
#pragma unroll
      for (int n = 0; n < 2; n++) {
        const int r = wn * 32 + n * 16 + (lane & 15);
        bfr[n] = *(const bf16x8*)(bufB + r * 128 + gsw);
      }
#pragma unroll
      for (int m = 0; m < 4; m++)
#pragma unroll
        for (int n = 0; n < 2; n++)
          acc[m][n] = __builtin_amdgcn_mfma_f32_16x16x32_bf16(
              af[m], bfr[n], acc[m][n], 0, 0, 0);
    }
    __syncthreads();
  }
#undef STAGE

  float e0c[2], e1c[2];
  int cols[2];
#pragma unroll
  for (int n = 0; n < 2; n++) {
    cols[n] = n0 + wn * 32 + n * 16 + (lane & 15);
    e0c[n] = E0[cols[n]];
    e1c[n] = E1[cols[n]];
  }
#pragma unroll
  for (int m = 0; m < 4; m++) {
    const int rbase = m0 + wm * 64 + m * 16 + ((lane >> 4) << 2);
#pragma unroll
    for (int j = 0; j < 4; j++) {
      const int row = rbase + j;
      const f32x2 iv = tst[row];
#pragma unroll
      for (int n = 0; n < 2; n++)
        C[(size_t)row * DD + cols[n]] =
            f2bf(iv[0] * acc[m][n][j] - iv[1] * e1c[n] + e0c[n]);
    }
  }
}

// ---------------- fused depth(I) + width(I+1) in basis form -----------------
template <int I>
__global__ __launch_bounds__(256) void fused_dw(
    const short* __restrict__ h2s, const short* __restrict__ b0,
    short* __restrict__ hout, f32x2* __restrict__ tst, float* __restrict__ Cc,
    float* __restrict__ ST, const float* __restrict__ Bp,
    const float* __restrict__ s_b, const float* __restrict__ A_m,
    const float* __restrict__ A_r, const float* __restrict__ s_a,
    const float* __restrict__ S0w, const float* __restrict__ T0d,
    const short* __restrict__ gwm, const short* __restrict__ gwr,
    const short* __restrict__ gwb) {
  constexpr int NB = I + 1;   // width block index
  constexpr int NP = 3 - I;   // # of gw tables to dot (l = NB..3)
  const int wave = threadIdx.x >> 6;
  const int lane = threadIdx.x & 63;
  const int tok = blockIdx.x * 4 + wave;

  const short* vt = h2s + ((size_t)I * NTOK + tok) * DD;
  const short* bases[I + 1];
  bases[0] = b0 + (size_t)tok * DD;
#pragma unroll
  for (int k = 1; k <= I; k++)
    bases[k] = h2s + ((size_t)(k - 1) * NTOK + tok) * DD;

  bf16x8 h2r[4];
#pragma unroll
  for (int j = 0; j < 4; j++)
    h2r[j] = *(const bf16x8*)(vt + lane * 8 + j * 512);

  // ---- phase 1: dots on v = h2^I ----
  float o = 0.f;
  float Gr[I + 2] = {};   // Gr[k]=v.b_k (k<=I), Gr[I+1]=v.v
  float Tb[4] = {0, 0, 0, 0};
  float Pn[NP][5];
#pragma unroll
  for (int li = 0; li < NP; li++)
#pragma unroll
    for (int m = 0; m < 5; m++) Pn[li][m] = 0.f;

#pragma unroll
  for (int j = 0; j < 4; j++) {
    const int d0 = lane * 8 + j * 512;
    bf16x8 bsv[I + 1];
#pragma unroll
    for (int k = 0; k <= I; k++) bsv[k] = *(const bf16x8*)(bases[k] + d0);
    bf16x8 wbv[4];
#pragma unroll
    for (int p = 0; p < 4; p++)
      wbv[p] = *(const bf16x8*)(gwb + ((size_t)I * DD + d0 + 2 * p) * 4);
    bf16x8 wmv[NP], wrv[NP][4];
#pragma unroll
    for (int li = 0; li < NP; li++) {
      const int l = NB + li;
      wmv[li] = *(const bf16x8*)(gwm + l * DD + d0);
#pragma unroll
      for (int p = 0; p < 4; p++)
        wrv[li][p] = *(const bf16x8*)(gwr + ((size_t)l * DD + d0 + 2 * p) * 4);
    }
#pragma unroll
    for (int q = 0; q < 8; q++) {
      const float hv = bf2f(h2r[j][q]);
      o += hv;
      Gr[I + 1] += hv * hv;
#pragma unroll
      for (int k = 0; k <= I; k++) Gr[k] += hv * bf2f(bsv[k][q]);
#pragma unroll
      for (int n = 0; n < 4; n++)
        Tb[n] += hv * bf2f(wbv[q >> 1][(q & 1) * 4 + n]);
#pragma unroll
      for (int li = 0; li < NP; li++) {
        Pn[li][0] += hv * bf2f(wmv[li][q]);
#pragma unroll
        for (int m = 0; m < 4; m++)
          Pn[li][1 + m] += hv * bf2f(wrv[li][q >> 1][(q & 1) * 4 + m]);
      }
    }
  }
  o = wred(o);
#pragma unroll
  for (int k = 0; k <= I + 1; k++) Gr[k] = wred(Gr[k]);
#pragma unroll
  for (int n = 0; n < 4; n++) Tb[n] = wred(Tb[n]);
#pragma unroll
  for (int li = 0; li < NP; li++)
#pragma unroll
    for (int m = 0; m < 5; m++) Pn[li][m] = wred(Pn[li][m]);

  // ---- phase 2: coefficient algebra (wave-uniform) ----
  float* STt = ST + (size_t)tok * STS;
  float* Ct = Cc + (size_t)tok * 16;
  float ofull[I + 2], Gf[I + 2][I + 2], Pf[I + 2][5], Cp[4][I + 2];
#pragma unroll
  for (int k = 0; k <= I; k++) ofull[k] = STt[k];
  ofull[I + 1] = o;
#pragma unroll
  for (int k = 0; k <= I; k++)
#pragma unroll
    for (int j2 = 0; j2 <= I; j2++) Gf[k][j2] = STt[4 + k * 4 + j2];
#pragma unroll
  for (int k = 0; k <= I; k++) { Gf[k][I + 1] = Gr[k]; Gf[I + 1][k] = Gr[k]; }
  Gf[I + 1][I + 1] = Gr[I + 1];
#pragma unroll
  for (int k = 0; k <= I; k++)
#pragma unroll
    for (int m = 0; m < 5; m++) Pf[k][m] = STt[pofs(k, NB) + m];
#pragma unroll
  for (int m = 0; m < 5; m++) Pf[I + 1][m] = Pn[0][m];
#pragma unroll
  for (int n = 0; n < 4; n++)
#pragma unroll
    for (int k = 0; k <= I; k++) Cp[n][k] = Ct[n * 4 + k];

  // depth coefficients Bv (block I)
  {
    const float mu2 = o * (1.f / DD);
    const float inv2 = rsqrtf(Gr[I + 1] * (1.f / DD) - mu2 * mu2 + EPSF);
    const float sb = s_b[I];
#pragma unroll
    for (int n = 0; n < 4; n++)
      Cp[n][I + 1] = Bp[I * 4 + n] +
                     sb * tanhf(inv2 * (Tb[n] - mu2 * T0d[I * 4 + n]));
  }

  // width coefficients Am/Ar (block NB) from Gram-expanded stats
  const float sa = s_a[NB];
  float Am[4], Ar[4][4];
#pragma unroll
  for (int n = 0; n < 4; n++) {
    float sH = 0.f, sH2 = 0.f;
#pragma unroll
    for (int k = 0; k <= I + 1; k++) {
      sH += Cp[n][k] * ofull[k];
#pragma unroll
      for (int j2 = 0; j2 <= I + 1; j2++)
        sH2 += Cp[n][k] * Cp[n][j2] * Gf[k][j2];
    }
    const float mu = sH * (1.f / DD);
    const float inv = rsqrtf(sH2 * (1.f / DD) - mu * mu + EPSF);
    float S1[5];
#pragma unroll
    for (int m = 0; m < 5; m++) {
      S1[m] = 0.f;
#pragma unroll
      for (int k = 0; k <= I + 1; k++) S1[m] += Cp[n][k] * Pf[k][m];
    }
    Am[n] = A_m[NB * 4 + n] +
            sa * tanhf(inv * (S1[0] - mu * S0w[NB * 5 + 0]));
#pragma unroll
    for (int m = 0; m < 4; m++)
      Ar[n][m] = A_r[NB * 16 + n * 4 + m] +
                 sa * tanhf(inv * (S1[1 + m] - mu * S0w[NB * 5 + 1 + m]));
  }

  // new coefficient matrix and hnorm combo coefficients
  float Cn[4][I + 2], hc[I + 2];
#pragma unroll
  for (int k = 0; k <= I + 1; k++) {
    hc[k] = 0.f;
#pragma unroll
    for (int n = 0; n < 4; n++) hc[k] += Am[n] * Cp[n][k];
  }
#pragma unroll
  for (int mr = 0; mr < 4; mr++)
#pragma unroll
    for (int k = 0; k <= I + 1; k++) {
      float acc = 0.f;
#pragma unroll
      for (int n = 0; n < 4; n++) acc += Ar[n][mr] * Cp[n][k];
      Cn[mr][k] = acc;
    }

  if (lane == 0) {
    // tst from Gram algebra (no reduction pass needed)
    float sh = 0.f, sh2 = 0.f;
#pragma unroll
    for (int k = 0; k <= I + 1; k++) {
      sh += hc[k] * ofull[k];
#pragma unroll
      for (int j2 = 0; j2 <= I + 1; j2++) sh2 += hc[k] * hc[j2] * Gf[k][j2];
    }
    const float mu = sh * (1.f / DD);
    const float inv = rsqrtf(sh2 * (1.f / DD) - mu * mu + EPSF);
    f32x2 t; t[0] = inv; t[1] = mu * inv;
    tst[tok] = t;
    // store-forward: o, Gram row, future-P rows, new C
    STt[I + 1] = o;
#pragma unroll
    for (int k = 0; k <= I + 1; k++) {
      STt[4 + (I + 1) * 4 + k] = Gf[I + 1][k];
      STt[4 + k * 4 + (I + 1)] = Gf[k][I + 1];
    }
#pragma unroll
    for (int li = 1; li < NP; li++)
#pragma unroll
      for (int m = 0; m < 5; m++) STt[pofs(I + 1, NB + li) + m] = Pn[li][m];
#pragma unroll
    for (int n = 0; n < 4; n++)
#pragma unroll
      for (int k = 0; k <= I + 1; k++) Ct[n * 4 + k] = Cn[n][k];
  }

  // ---- phase 3: hnorm = sum_k hc[k] * b_k ----
  short* hw = hout + (size_t)tok * DD;
#pragma unroll
  for (int j = 0; j < 4; j++) {
    const int d0 = lane * 8 + j * 512;
    bf16x8 bsv[I + 1];
#pragma unroll
    for (int k = 0; k <= I; k++) bsv[k] = *(const bf16x8*)(bases[k] + d0);
    bf16x8 ho;
#pragma unroll
    for (int q = 0; q < 8; q++) {
      float a = hc[I + 1] * bf2f(h2r[j][q]);
#pragma unroll
      for (int k = 0; k <= I; k++) a += hc[k] * bf2f(bsv[k][q]);
      ho[q] = f2bf(a);
    }
    *(bf16x8*)(hw + d0) = ho;
  }
}

// ---------------- final depth (block 3) + output combo ----------------------
__global__ __launch_bounds__(256) void depth_last(
    const short* __restrict__ h2s, const short* __restrict__ b0,
    float* __restrict__ out, const float* __restrict__ Cc,
    const float* __restrict__ Bp, const float* __restrict__ s_b,
    const float* __restrict__ T0d, const short* __restrict__ gwb) {
  const int wave = threadIdx.x >> 6;
  const int lane = threadIdx.x & 63;
  const int tok = blockIdx.x * 4 + wave;
  const short* vt = h2s + ((size_t)3 * NTOK + tok) * DD;

  bf16x8 h2r[4];
  float s1 = 0.f, s2 = 0.f, Tb[4] = {0, 0, 0, 0};
#pragma unroll
  for (int j = 0; j < 4; j++) {
    const int d0 = lane * 8 + j * 512;
    h2r[j] = *(const bf16x8*)(vt + d0);
    bf16x8 wbv[4];
#pragma unroll
    for (int p = 0; p < 4; p++)
      wbv[p] = *(const bf16x8*)(gwb + ((size_t)3 * DD + d0 + 2 * p) * 4);
#pragma unroll
    for (int q = 0; q < 8; q++) {
      const float hv = bf2f(h2r[j][q]);
      s1 += hv; s2 += hv * hv;
#pragma unroll
      for (int n = 0; n < 4; n++)
        Tb[n] += hv * bf2f(wbv[q >> 1][(q & 1) * 4 + n]);
    }
  }
  s1 = wred(s1); s2 = wred(s2);
#pragma unroll
  for (int n = 0; n < 4; n++) Tb[n] = wred(Tb[n]);

  const float mu = s1 * (1.f / DD);
  const float inv = rsqrtf(s2 * (1.f / DD) - mu * mu + EPSF);
  const float sb = s_b[3];
  float bsum = 0.f;
#pragma unroll
  for (int n = 0; n < 4; n++)
    bsum += Bp[12 + n] + sb * tanhf(inv * (Tb[n] - mu * T0d[12 + n]));

  const float* Ct = Cc + (size_t)tok * 16;
  float e[4];
#pragma unroll
  for (int k = 0; k < 4; k++) {
    e[k] = 0.f;
#pragma unroll
    for (int n = 0; n < 4; n++) e[k] += Ct[n * 4 + k];
  }

  const short* bases[4];
  bases[0] = b0 + (size_t)tok * DD;
#pragma unroll
  for (int k = 1; k < 4; k++)
    bases[k] = h2s + ((size_t)(k - 1) * NTOK + tok) * DD;

  float* orow = out + (size_t)tok * DD;
#pragma unroll
  for (int j = 0; j < 4; j++) {
    const int d0 = lane * 8 + j * 512;
    bf16x8 bsv[4];
#pragma unroll
    for (int k = 0; k < 4; k++) bsv[k] = *(const bf16x8*)(bases[k] + d0);
    f32x4 o0, o1;
#pragma unroll
    for (int q = 0; q < 8; q++) {
      float s = bsum * bf2f(h2r[j][q]);
#pragma unroll
      for (int k = 0; k < 4; k++) s += e[k] * bf2f(bsv[k][q]);
      if (q < 4) o0[q] = s; else o1[q - 4] = s;
    }
    *(f32x4*)(orow + d0) = o0;
    *(f32x4*)(orow + d0 + 4) = o1;
  }
}

extern "C" void kernel_launch(void* const* d_in, const int* in_sizes, int n_in,
                              void* d_out, int out_size, void* d_ws,
                              size_t ws_size, hipStream_t stream) {
  const float* x = (const float*)d_in[0];
  const float* A_m = (const float*)d_in[1];
  const float* A_r = (const float*)d_in[2];
  const float* Bp = (const float*)d_in[3];
  const float* W_m = (const float*)d_in[4];
  const float* W_r = (const float*)d_in[5];
  const float* W_b = (const float*)d_in[6];
  const float* s_a = (const float*)d_in[7];
  const float* s_b = (const float*)d_in[8];
  const float* dyn_gamma = (const float*)d_in[9];
  const float* norm_gamma = (const float*)d_in[10];
  const float* norm_beta = (const float*)d_in[11];
  const float* Wblk = (const float*)d_in[12];
  const float* bblk = (const float*)d_in[13];
  float* out = (float*)d_out;

  char* ws = (char*)d_ws;
  short* b0 = (short*)(ws);                    // 16 MiB: bf16 copy of x
  short* h2s = (short*)(ws + 16777216);        // 4 slots x 16 MiB
  short* hnorm = (short*)(ws + 83886080);      // 16 MiB
  char* aux = ws + 100663296;
  short* gwm = (short*)(aux);                  // 16 KiB
  short* gwr = (short*)(aux + 16384);          // 64 KiB
  short* gwb = (short*)(aux + 81920);          // 64 KiB
  float* rb = (float*)(aux + 147456);          // 32 KiB
  float* S0w = (float*)(aux + 180224);
  float* T0d = (float*)(aux + 181248);
  f32x2* tst = (f32x2*)(aux + 182272);         // 32 KiB
  float* E0 = (float*)(aux + 215040);          // 32 KiB
  float* E1 = (float*)(aux + 247808);          // 32 KiB
  float* Cc = (float*)(aux + 280576);          // 256 KiB: C[tok][4][4]
  float* ST = (float*)(aux + 542720);          // 1.25 MiB: stats[tok][80]
  short* Wt = (short*)d_out;  // recomputed every call, overwritten at end

  dim3 tb(256);
  prep_pack<<<32, tb, 0, stream>>>(W_m, W_r, W_b, dyn_gamma, norm_gamma,
                                   norm_beta, gwm, gwr, gwb, rb);
  prep_sums<<<4, dim3(64), 0, stream>>>(W_m, W_r, W_b, dyn_gamma, S0w, T0d);
  transpose_wblk<<<dim3(32, 32, 4), tb, 0, stream>>>(Wblk, norm_gamma, Wt);
  row_sums<<<dim3(512, 4), tb, 0, stream>>>(Wt, rb, bblk, E0, E1);
  width0_kernel<<<1024, tb, 0, stream>>>(x, b0, hnorm, tst, Cc, ST, A_m, A_r,
                                         gwm, gwr, s_a, S0w);
  for (int i = 0; i < LL; i++) {
    gemm_kernel<<<512, dim3(512), 0, stream>>>(
        hnorm, Wt + (size_t)i * DD * DD, tst, E0 + i * DD, E1 + i * DD,
        h2s + (size_t)i * NTOK * DD);
    if (i == 0)
      fused_dw<0><<<1024, tb, 0, stream>>>(h2s, b0, hnorm, tst, Cc, ST, Bp,
                                           s_b, A_m, A_r, s_a, S0w, T0d, gwm,
                                           gwr, gwb);
    else if (i == 1)
      fused_dw<1><<<1024, tb, 0, stream>>>(h2s, b0, hnorm, tst, Cc, ST, Bp,
                                           s_b, A_m, A_r, s_a, S0w, T0d, gwm,
                                           gwr, gwb);
    else if (i == 2)
      fused_dw<2><<<1024, tb, 0, stream>>>(h2s, b0, hnorm, tst, Cc, ST, Bp,
                                           s_b, A_m, A_r, s_a, S0w, T0d, gwm,
                                           gwr, gwb);
    else
      depth_last<<<1024, tb, 0, stream>>>(h2s, b0, out, Cc, Bp, s_b, T0d, gwb);
  }
}

// Round 10
// 326.605 us; speedup vs baseline: 1.2911x; 1.0004x over previous
//
#include <hip/hip_runtime.h>
#include <hip/hip_bf16.h>

// HCNet: L=4 hyper-connection blocks, N=4, D=2048, B*T=4096 tokens.
// R10: gemm converted to counted-vmcnt + raw-barrier pipeline (T4): STAGE
// issued before a vmcnt(4) wait, so prefetch loads span the barrier pair
// instead of being drained by __syncthreads' vmcnt(0). + s_setprio (T5)
// around the MFMA cluster. Everything else unchanged from R9 (basis form).

#define DD 2048
#define NN 4
#define LL 4
#define NTOK 4096
#define EPSF 1e-5f
#define STS 80  // ST row stride (floats)

typedef __attribute__((ext_vector_type(8))) short bf16x8;
typedef __attribute__((ext_vector_type(4))) float f32x4;
typedef __attribute__((ext_vector_type(2))) float f32x2;

__device__ __forceinline__ float bf2f(short u) {
  union { unsigned int i; float f; } v;
  v.i = ((unsigned int)(unsigned short)u) << 16;
  return v.f;
}
__device__ __forceinline__ short f2bf(float f) {
  __hip_bfloat16 h = __float2bfloat16(f);
  short s;
  __builtin_memcpy(&s, &h, 2);
  return s;
}
__device__ __forceinline__ float wred(float v) {
#pragma unroll
  for (int off = 32; off > 0; off >>= 1) v += __shfl_xor(v, off, 64);
  return v;
}
__device__ __forceinline__ void ld16(const void* g, void* l) {
  __builtin_amdgcn_global_load_lds(
      (const __attribute__((address_space(1))) void*)g,
      (__attribute__((address_space(3))) void*)l, 16, 0, 0);
}
__host__ __device__ constexpr int pofs(int k, int l) {
  return k == 0 ? 20 + l * 5
       : k == 1 ? 40 + (l - 1) * 5
       : k == 2 ? 55 + (l - 2) * 5
                : 65;
}

// ---------------- prep: gamma-scaled bf16 tables + beta/gamma ratio ---------
__global__ __launch_bounds__(256) void prep_pack(
    const float* __restrict__ W_m, const float* __restrict__ W_r,
    const float* __restrict__ W_b, const float* __restrict__ dyn_gamma,
    const float* __restrict__ norm_gamma, const float* __restrict__ norm_beta,
    short* __restrict__ gwm, short* __restrict__ gwr, short* __restrict__ gwb,
    float* __restrict__ rb) {
  const int i = blockIdx.x * 256 + threadIdx.x;  // over L*D = 8192
  const float g = dyn_gamma[i];
  gwm[i] = f2bf(g * W_m[i]);
  f32x4 r = *(const f32x4*)(W_r + (size_t)i * 4);
  f32x4 b = *(const f32x4*)(W_b + (size_t)i * 4);
  short ro[4], bo[4];
#pragma unroll
  for (int k = 0; k < 4; k++) { ro[k] = f2bf(g * r[k]); bo[k] = f2bf(g * b[k]); }
  *(unsigned long long*)(gwr + (size_t)i * 4) = *(unsigned long long*)ro;
  *(unsigned long long*)(gwb + (size_t)i * 4) = *(unsigned long long*)bo;
  rb[i] = norm_beta[i] / norm_gamma[i];
}

// ---------------- token-independent sums S0w[l][5], T0d[l][4] ---------------
__global__ __launch_bounds__(64) void prep_sums(
    const float* __restrict__ W_m, const float* __restrict__ W_r,
    const float* __restrict__ W_b, const float* __restrict__ dyn_gamma,
    float* __restrict__ S0w, float* __restrict__ T0d) {
  const int l = blockIdx.x;
  const int lane = threadIdx.x;
  float s[5] = {0, 0, 0, 0, 0}, t[4] = {0, 0, 0, 0};
  for (int d = lane; d < DD; d += 64) {
    const float g = dyn_gamma[l * DD + d];
    s[0] += g * W_m[l * DD + d];
    f32x4 r = *(const f32x4*)(W_r + ((size_t)l * DD + d) * 4);
    f32x4 b = *(const f32x4*)(W_b + ((size_t)l * DD + d) * 4);
#pragma unroll
    for (int m = 0; m < 4; m++) { s[1 + m] += g * r[m]; t[m] += g * b[m]; }
  }
#pragma unroll
  for (int m = 0; m < 5; m++) s[m] = wred(s[m]);
#pragma unroll
  for (int n = 0; n < 4; n++) t[n] = wred(t[n]);
  if (lane == 0) {
#pragma unroll
    for (int m = 0; m < 5; m++) S0w[l * 5 + m] = s[m];
#pragma unroll
    for (int n = 0; n < 4; n++) T0d[l * 4 + n] = t[n];
  }
}

// ------- transpose Wblk[l][d][e] (f32) -> Wt[l][e][d] = norm_g[d]*W (bf16) --
__global__ __launch_bounds__(256) void transpose_wblk(
    const float* __restrict__ W, const float* __restrict__ norm_gamma,
    short* __restrict__ Wt) {
  __shared__ float tile[64][65];
  const int blk = blockIdx.z;
  const int c0 = blockIdx.x * 64;
  const int r0 = blockIdx.y * 64;
  const float* Ws = W + (size_t)blk * DD * DD;
  short* Wd = Wt + (size_t)blk * DD * DD;
  const int tx = threadIdx.x & 63, ty = threadIdx.x >> 6;
#pragma unroll
  for (int r = 0; r < 16; r++) {
    const int row = ty + r * 4;
    tile[row][tx] = Ws[(size_t)(r0 + row) * DD + c0 + tx];
  }
  const float gsc = norm_gamma[blk * DD + r0 + tx];
  __syncthreads();
#pragma unroll
  for (int r = 0; r < 16; r++) {
    const int row = ty + r * 4;
    Wd[(size_t)(c0 + row) * DD + r0 + tx] = f2bf(tile[tx][row] * gsc);
  }
}

// ---------------- row sums of Wt': E1 = sum_d Wt', E0 = sum_d rb*Wt' + bias -
__global__ __launch_bounds__(256) void row_sums(
    const short* __restrict__ Wt, const float* __restrict__ rb,
    const float* __restrict__ bblk, float* __restrict__ E0,
    float* __restrict__ E1) {
  const int l = blockIdx.y;
  const int e = blockIdx.x * 4 + (threadIdx.x >> 6);
  const int lane = threadIdx.x & 63;
  const short* row = Wt + ((size_t)l * DD + e) * DD;
  const float* rbl = rb + l * DD;
  float s1 = 0.f, s0 = 0.f;
#pragma unroll
  for (int it = 0; it < 4; it++) {
    const int d0 = lane * 8 + it * 512;
    bf16x8 w = *(const bf16x8*)(row + d0);
    f32x4 r0 = *(const f32x4*)(rbl + d0), r1 = *(const f32x4*)(rbl + d0 + 4);
#pragma unroll
    for (int q = 0; q < 8; q++) {
      const float wq = bf2f(w[q]);
      s1 += wq;
      s0 += wq * ((q < 4) ? r0[q] : r1[q - 4]);
    }
  }
  s1 = wred(s1); s0 = wred(s0);
  if (lane == 0) {
    E1[l * DD + e] = s1;
    E0[l * DD + e] = s0 + bblk[l * DD + e];
  }
}

// ---------------- width0: x-dots + block-0 coefficients + hnorm -------------
__global__ __launch_bounds__(256) void width0_kernel(
    const float* __restrict__ x, short* __restrict__ b0,
    short* __restrict__ hout, f32x2* __restrict__ tst, float* __restrict__ Cc,
    float* __restrict__ ST, const float* __restrict__ A_m,
    const float* __restrict__ A_r, const short* __restrict__ gwm,
    const short* __restrict__ gwr, const float* __restrict__ s_a,
    const float* __restrict__ S0w) {
  const int wave = threadIdx.x >> 6;
  const int lane = threadIdx.x & 63;
  const int tok = blockIdx.x * 4 + wave;
  const float* xr = x + (size_t)tok * DD;
  short* b0t = b0 + (size_t)tok * DD;

  bf16x8 xb[4];
#pragma unroll
  for (int j = 0; j < 4; j++) {
    const int d0 = lane * 8 + j * 512;
    f32x4 a = *(const f32x4*)(xr + d0);
    f32x4 b = *(const f32x4*)(xr + d0 + 4);
    bf16x8 p;
#pragma unroll
    for (int q = 0; q < 4; q++) { p[q] = f2bf(a[q]); p[4 + q] = f2bf(b[q]); }
    xb[j] = p;
    *(bf16x8*)(b0t + d0) = p;
  }

  float o = 0.f, qq = 0.f, P0[4][5];
#pragma unroll
  for (int l = 0; l < 4; l++)
#pragma unroll
    for (int m = 0; m < 5; m++) P0[l][m] = 0.f;

#pragma unroll
  for (int j = 0; j < 4; j++) {
    const int d0 = lane * 8 + j * 512;
    bf16x8 wmv[4], wrv[4][4];
#pragma unroll
    for (int l = 0; l < 4; l++) {
      wmv[l] = *(const bf16x8*)(gwm + l * DD + d0);
#pragma unroll
      for (int p = 0; p < 4; p++)
        wrv[l][p] = *(const bf16x8*)(gwr + ((size_t)l * DD + d0 + 2 * p) * 4);
    }
#pragma unroll
    for (int q = 0; q < 8; q++) {
      const float hv = bf2f(xb[j][q]);
      o += hv; qq += hv * hv;
#pragma unroll
      for (int l = 0; l < 4; l++) {
        P0[l][0] += hv * bf2f(wmv[l][q]);
#pragma unroll
        for (int m = 0; m < 4; m++)
          P0[l][1 + m] += hv * bf2f(wrv[l][q >> 1][(q & 1) * 4 + m]);
      }
    }
  }
  o = wred(o); qq = wred(qq);
#pragma unroll
  for (int l = 0; l < 4; l++)
#pragma unroll
    for (int m = 0; m < 5; m++) P0[l][m] = wred(P0[l][m]);

  // block-0 width coefficients (all H rows = x)
  const float sa = s_a[0];
  const float mu = o * (1.f / DD);
  const float inv = rsqrtf(qq * (1.f / DD) - mu * mu + EPSF);
  const float t0 = tanhf(inv * (P0[0][0] - mu * S0w[0]));
  float tm[4];
#pragma unroll
  for (int m = 0; m < 4; m++)
    tm[m] = tanhf(inv * (P0[0][1 + m] - mu * S0w[1 + m]));
  float amSum = 0.f, arCol[4] = {0, 0, 0, 0};
#pragma unroll
  for (int n = 0; n < 4; n++) {
    amSum += A_m[n] + sa * t0;
#pragma unroll
    for (int m = 0; m < 4; m++) arCol[m] += A_r[n * 4 + m] + sa * tm[m];
  }

  if (lane == 0) {
    const float sh = amSum * o;
    const float sh2 = amSum * amSum * qq;
    const float mu2 = sh * (1.f / DD);
    const float inv2 = rsqrtf(sh2 * (1.f / DD) - mu2 * mu2 + EPSF);
    f32x2 t; t[0] = inv2; t[1] = mu2 * inv2;
    tst[tok] = t;
    float* STt = ST + (size_t)tok * STS;
    STt[0] = o;
    STt[4] = qq;  // G[0][0]
#pragma unroll
    for (int l = 0; l < 4; l++)
#pragma unroll
      for (int m = 0; m < 5; m++) STt[pofs(0, l) + m] = P0[l][m];
    float* Ct = Cc + (size_t)tok * 16;
#pragma unroll
    for (int n = 0; n < 4; n++) Ct[n * 4] = arCol[n];
  }

  short* hw = hout + (size_t)tok * DD;
#pragma unroll
  for (int j = 0; j < 4; j++) {
    const int d0 = lane * 8 + j * 512;
    bf16x8 ho;
#pragma unroll
    for (int q = 0; q < 8; q++) ho[q] = f2bf(amSum * bf2f(xb[j][q]));
    *(bf16x8*)(hw + d0) = ho;
  }
}

// ---------------- block GEMM: h2 = LN-folded(h @ Wt') -----------------------
// Counted-vmcnt pipeline: STAGE(kt+1) issued first, vmcnt(4) waits only for
// stage(kt), raw barriers; prefetch loads stay in flight across the barrier.
__global__ __launch_bounds__(512) void gemm_kernel(
    const short* __restrict__ A, const short* __restrict__ Bt,
    const f32x2* __restrict__ tst, const float* __restrict__ E0,
    const float* __restrict__ E1, short* __restrict__ C) {
  __shared__ short lA[2][128 * 64];
  __shared__ short lB[2][128 * 64];
  const int tid = threadIdx.x;
  const int lane = tid & 63;
  const int wave = tid >> 6;
  const int bid = blockIdx.x;
  const int wg = (bid & 7) * 64 + (bid >> 3);
  const int m0 = (wg & 31) * 128, n0 = (wg >> 5) * 128;
  const int wm = wave >> 2;
  const int wn = wave & 3;

  f32x4 acc[4][2] = {};

#define STAGE(buf, kt)                                                        \
  {                                                                           \
    const int k0 = (kt) * 64;                                                 \
    _Pragma("unroll") for (int c = 0; c < 2; c++) {                           \
      const int idx = c * 512 + tid;                                          \
      const int row = idx >> 3;                                               \
      const int colsw = (((idx & 7) ^ (row & 7)) * 8);                        \
      ld16(A + (size_t)(m0 + row) * DD + k0 + colsw,                          \
           (char*)&lA[buf][0] + idx * 16);                                    \
      ld16(Bt + (size_t)(n0 + row) * DD + k0 + colsw,                         \
           (char*)&lB[buf][0] + idx * 16);                                    \
    }                                                                         \
  }

#define COMPUTE(cur)                                                          \
  {                                                                           \
    const char* bufA = (const char*)&lA[cur][0];                              \
    const char* bufB = (const char*)&lB[cur][0];                              \
    _Pragma("unroll") for (int kk = 0; kk < 2; ++kk) {                        \
      const int gsw = (kk * 64 + (lane >> 4) * 16) ^ ((lane & 7) << 4);       \
      bf16x8 af[4], bfr[2];                                                   \
      _Pragma("unroll") for (int m = 0; m < 4; m++) {                         \
        const int r = wm * 64 + m * 16 + (lane & 15);                         \
        af[m] = *(const bf16x8*)(bufA + r * 128 + gsw);                       \
      }                                                                       \
      _Pragma("unroll") for (int n = 0; n < 2; n++) {                         \
        const int r = wn * 32 + n * 16 + (lane & 15);                         \
        bfr[n] = *(const bf16x8*)(bufB + r * 128 + gsw);                      \
      }                                                                       \
      __builtin_amdgcn_s_setprio(1);                                          \
      _Pragma("unroll") for (int m = 0; m < 4; m++)                           \
        _Pragma("unroll") for (int n = 0; n < 2; n++)                         \
          acc[m][n] = __builtin_amdgcn_mfma_f32_16x16x32_bf16(                \
              af[m], bfr[n], acc[m][n], 0, 0, 0);                             \
      __builtin_amdgcn_s_setprio(0);                                          \
    }                                                                         \
  }

  STAGE(0, 0);
  for (int kt = 0; kt < 31; ++kt) {
    const int cur = kt & 1;
    STAGE(cur ^ 1, kt + 1);                       // 4 loads -> 8 outstanding
    asm volatile("s_waitcnt vmcnt(4)" ::: "memory");  // stage(kt) landed
    asm volatile("s_barrier" ::: "memory");           // all waves agree
    COMPUTE(cur);
    asm volatile("s_barrier" ::: "memory");           // reads of buf cur done
  }
  asm volatile("s_waitcnt vmcnt(0)" ::: "memory");
  asm volatile("s_barrier" ::: "memory");
  COMPUTE(1);
#undef STAGE
#undef COMPUTE

  float e0c[2], e1c[2];
  int cols[2];
#pragma unroll
  for (int n = 0; n < 2; n++) {
    cols[n] = n0 + wn * 32 + n * 16 + (lane & 15);
    e0c[n] = E0[cols[n]];
    e1c[n] = E1[cols[n]];
  }
#pragma unroll
  for (int m = 0; m < 4; m++) {
    const int rbase = m0 + wm * 64 + m * 16 + ((lane >> 4) << 2);
#pragma unroll
    for (int j = 0; j < 4; j++) {
      const int row = rbase + j;
      const f32x2 iv = tst[row];
#pragma unroll
      for (int n = 0; n < 2; n++)
        C[(size_t)row * DD + cols[n]] =
            f2bf(iv[0] * acc[m][n][j] - iv[1] * e1c[n] + e0c[n]);
    }
  }
}

// ---------------- fused depth(I) + width(I+1) in basis form -----------------
template <int I>
__global__ __launch_bounds__(256) void fused_dw(
    const short* __restrict__ h2s, const short* __restrict__ b0,
    short* __restrict__ hout, f32x2* __restrict__ tst, float* __restrict__ Cc,
    float* __restrict__ ST, const float* __restrict__ Bp,
    const float* __restrict__ s_b, const float* __restrict__ A_m,
    const float* __restrict__ A_r, const float* __restrict__ s_a,
    const float* __restrict__ S0w, const float* __restrict__ T0d,
    const short* __restrict__ gwm, const short* __restrict__ gwr,
    const short* __restrict__ gwb) {
  constexpr int NB = I + 1;   // width block index
  constexpr int NP = 3 - I;   // # of gw tables to dot (l = NB..3)
  const int wave = threadIdx.x >> 6;
  const int lane = threadIdx.x & 63;
  const int tok = blockIdx.x * 4 + wave;

  const short* vt = h2s + ((size_t)I * NTOK + tok) * DD;
  const short* bases[I + 1];
  bases[0] = b0 + (size_t)tok * DD;
#pragma unroll
  for (int k = 1; k <= I; k++)
    bases[k] = h2s + ((size_t)(k - 1) * NTOK + tok) * DD;

  bf16x8 h2r[4];
#pragma unroll
  for (int j = 0; j < 4; j++)
    h2r[j] = *(const bf16x8*)(vt + lane * 8 + j * 512);

  // ---- phase 1: dots on v = h2^I ----
  float o = 0.f;
  float Gr[I + 2] = {};   // Gr[k]=v.b_k (k<=I), Gr[I+1]=v.v
  float Tb[4] = {0, 0, 0, 0};
  float Pn[NP][5];
#pragma unroll
  for (int li = 0; li < NP; li++)
#pragma unroll
    for (int m = 0; m < 5; m++) Pn[li][m] = 0.f;

#pragma unroll
  for (int j = 0; j < 4; j++) {
    const int d0 = lane * 8 + j * 512;
    bf16x8 bsv[I + 1];
#pragma unroll
    for (int k = 0; k <= I; k++) bsv[k] = *(const bf16x8*)(bases[k] + d0);
    bf16x8 wbv[4];
#pragma unroll
    for (int p = 0; p < 4; p++)
      wbv[p] = *(const bf16x8*)(gwb + ((size_t)I * DD + d0 + 2 * p) * 4);
    bf16x8 wmv[NP], wrv[NP][4];
#pragma unroll
    for (int li = 0; li < NP; li++) {
      const int l = NB + li;
      wmv[li] = *(const bf16x8*)(gwm + l * DD + d0);
#pragma unroll
      for (int p = 0; p < 4; p++)
        wrv[li][p] = *(const bf16x8*)(gwr + ((size_t)l * DD + d0 + 2 * p) * 4);
    }
#pragma unroll
    for (int q = 0; q < 8; q++) {
      const float hv = bf2f(h2r[j][q]);
      o += hv;
      Gr[I + 1] += hv * hv;
#pragma unroll
      for (int k = 0; k <= I; k++) Gr[k] += hv * bf2f(bsv[k][q]);
#pragma unroll
      for (int n = 0; n < 4; n++)
        Tb[n] += hv * bf2f(wbv[q >> 1][(q & 1) * 4 + n]);
#pragma unroll
      for (int li = 0; li < NP; li++) {
        Pn[li][0] += hv * bf2f(wmv[li][q]);
#pragma unroll
        for (int m = 0; m < 4; m++)
          Pn[li][1 + m] += hv * bf2f(wrv[li][q >> 1][(q & 1) * 4 + m]);
      }
    }
  }
  o = wred(o);
#pragma unroll
  for (int k = 0; k <= I + 1; k++) Gr[k] = wred(Gr[k]);
#pragma unroll
  for (int n = 0; n < 4; n++) Tb[n] = wred(Tb[n]);
#pragma unroll
  for (int li = 0; li < NP; li++)
#pragma unroll
    for (int m = 0; m < 5; m++) Pn[li][m] = wred(Pn[li][m]);

  // ---- phase 2: coefficient algebra (wave-uniform) ----
  float* STt = ST + (size_t)tok * STS;
  float* Ct = Cc + (size_t)tok * 16;
  float ofull[I + 2], Gf[I + 2][I + 2], Pf[I + 2][5], Cp[4][I + 2];
#pragma unroll
  for (int k = 0; k <= I; k++) ofull[k] = STt[k];
  ofull[I + 1] = o;
#pragma unroll
  for (int k = 0; k <= I; k++)
#pragma unroll
    for (int j2 = 0; j2 <= I; j2++) Gf[k][j2] = STt[4 + k * 4 + j2];
#pragma unroll
  for (int k = 0; k <= I; k++) { Gf[k][I + 1] = Gr[k]; Gf[I + 1][k] = Gr[k]; }
  Gf[I + 1][I + 1] = Gr[I + 1];
#pragma unroll
  for (int k = 0; k <= I; k++)
#pragma unroll
    for (int m = 0; m < 5; m++) Pf[k][m] = STt[pofs(k, NB) + m];
#pragma unroll
  for (int m = 0; m < 5; m++) Pf[I + 1][m] = Pn[0][m];
#pragma unroll
  for (int n = 0; n < 4; n++)
#pragma unroll
    for (int k = 0; k <= I; k++) Cp[n][k] = Ct[n * 4 + k];

  // depth coefficients Bv (block I)
  {
    const float mu2 = o * (1.f / DD);
    const float inv2 = rsqrtf(Gr[I + 1] * (1.f / DD) - mu2 * mu2 + EPSF);
    const float sb = s_b[I];
#pragma unroll
    for (int n = 0; n < 4; n++)
      Cp[n][I + 1] = Bp[I * 4 + n] +
                     sb * tanhf(inv2 * (Tb[n] - mu2 * T0d[I * 4 + n]));
  }

  // width coefficients Am/Ar (block NB) from Gram-expanded stats
  const float sa = s_a[NB];
  float Am[4], Ar[4][4];
#pragma unroll
  for (int n = 0; n < 4; n++) {
    float sH = 0.f, sH2 = 0.f;
#pragma unroll
    for (int k = 0; k <= I + 1; k++) {
      sH += Cp[n][k] * ofull[k];
#pragma unroll
      for (int j2 = 0; j2 <= I + 1; j2++)
        sH2 += Cp[n][k] * Cp[n][j2] * Gf[k][j2];
    }
    const float mu = sH * (1.f / DD);
    const float inv = rsqrtf(sH2 * (1.f / DD) - mu * mu + EPSF);
    float S1[5];
#pragma unroll
    for (int m = 0; m < 5; m++) {
      S1[m] = 0.f;
#pragma unroll
      for (int k = 0; k <= I + 1; k++) S1[m] += Cp[n][k] * Pf[k][m];
    }
    Am[n] = A_m[NB * 4 + n] +
            sa * tanhf(inv * (S1[0] - mu * S0w[NB * 5 + 0]));
#pragma unroll
    for (int m = 0; m < 4; m++)
      Ar[n][m] = A_r[NB * 16 + n * 4 + m] +
                 sa * tanhf(inv * (S1[1 + m] - mu * S0w[NB * 5 + 1 + m]));
  }

  // new coefficient matrix and hnorm combo coefficients
  float Cn[4][I + 2], hc[I + 2];
#pragma unroll
  for (int k = 0; k <= I + 1; k++) {
    hc[k] = 0.f;
#pragma unroll
    for (int n = 0; n < 4; n++) hc[k] += Am[n] * Cp[n][k];
  }
#pragma unroll
  for (int mr = 0; mr < 4; mr++)
#pragma unroll
    for (int k = 0; k <= I + 1; k++) {
      float acc = 0.f;
#pragma unroll
      for (int n = 0; n < 4; n++) acc += Ar[n][mr] * Cp[n][k];
      Cn[mr][k] = acc;
    }

  if (lane == 0) {
    float sh = 0.f, sh2 = 0.f;
#pragma unroll
    for (int k = 0; k <= I + 1; k++) {
      sh += hc[k] * ofull[k];
#pragma unroll
      for (int j2 = 0; j2 <= I + 1; j2++) sh2 += hc[k] * hc[j2] * Gf[k][j2];
    }
    const float mu = sh * (1.f / DD);
    const float inv = rsqrtf(sh2 * (1.f / DD) - mu * mu + EPSF);
    f32x2 t; t[0] = inv; t[1] = mu * inv;
    tst[tok] = t;
    STt[I + 1] = o;
#pragma unroll
    for (int k = 0; k <= I + 1; k++) {
      STt[4 + (I + 1) * 4 + k] = Gf[I + 1][k];
      STt[4 + k * 4 + (I + 1)] = Gf[k][I + 1];
    }
#pragma unroll
    for (int li = 1; li < NP; li++)
#pragma unroll
      for (int m = 0; m < 5; m++) STt[pofs(I + 1, NB + li) + m] = Pn[li][m];
#pragma unroll
    for (int n = 0; n < 4; n++)
#pragma unroll
      for (int k = 0; k <= I + 1; k++) Ct[n * 4 + k] = Cn[n][k];
  }

  // ---- phase 3: hnorm = sum_k hc[k] * b_k ----
  short* hw = hout + (size_t)tok * DD;
#pragma unroll
  for (int j = 0; j < 4; j++) {
    const int d0 = lane * 8 + j * 512;
    bf16x8 bsv[I + 1];
#pragma unroll
    for (int k = 0; k <= I; k++) bsv[k] = *(const bf16x8*)(bases[k] + d0);
    bf16x8 ho;
#pragma unroll
    for (int q = 0; q < 8; q++) {
      float a = hc[I + 1] * bf2f(h2r[j][q]);
#pragma unroll
      for (int k = 0; k <= I; k++) a += hc[k] * bf2f(bsv[k][q]);
      ho[q] = f2bf(a);
    }
    *(bf16x8*)(hw + d0) = ho;
  }
}

// ---------------- final depth (block 3) + output combo ----------------------
__global__ __launch_bounds__(256) void depth_last(
    const short* __restrict__ h2s, const short* __restrict__ b0,
    float* __restrict__ out, const float* __restrict__ Cc,
    const float* __restrict__ Bp, const float* __restrict__ s_b,
    const float* __restrict__ T0d, const short* __restrict__ gwb) {
  const int wave = threadIdx.x >> 6;
  const int lane = threadIdx.x & 63;
  const int tok = blockIdx.x * 4 + wave;
  const short* vt = h2s + ((size_t)3 * NTOK + tok) * DD;

  bf16x8 h2r[4];
  float s1 = 0.f, s2 = 0.f, Tb[4] = {0, 0, 0, 0};
#pragma unroll
  for (int j = 0; j < 4; j++) {
    const int d0 = lane * 8 + j * 512;
    h2r[j] = *(const bf16x8*)(vt + d0);
    bf16x8 wbv[4];
#pragma unroll
    for (int p = 0; p < 4; p++)
      wbv[p] = *(const bf16x8*)(gwb + ((size_t)3 * DD + d0 + 2 * p) * 4);
#pragma unroll
    for (int q = 0; q < 8; q++) {
      const float hv = bf2f(h2r[j][q]);
      s1 += hv; s2 += hv * hv;
#pragma unroll
      for (int n = 0; n < 4; n++)
        Tb[n] += hv * bf2f(wbv[q >> 1][(q & 1) * 4 + n]);
    }
  }
  s1 = wred(s1); s2 = wred(s2);
#pragma unroll
  for (int n = 0; n < 4; n++) Tb[n] = wred(Tb[n]);

  const float mu = s1 * (1.f / DD);
  const float inv = rsqrtf(s2 * (1.f / DD) - mu * mu + EPSF);
  const float sb = s_b[3];
  float bsum = 0.f;
#pragma unroll
  for (int n = 0; n < 4; n++)
    bsum += Bp[12 + n] + sb * tanhf(inv * (Tb[n] - mu * T0d[12 + n]));

  const float* Ct = Cc + (size_t)tok * 16;
  float e[4];
#pragma unroll
  for (int k = 0; k < 4; k++) {
    e[k] = 0.f;
#pragma unroll
    for (int n = 0; n < 4; n++) e[k] += Ct[n * 4 + k];
  }

  const short* bases[4];
  bases[0] = b0 + (size_t)tok * DD;
#pragma unroll
  for (int k = 1; k < 4; k++)
    bases[k] = h2s + ((size_t)(k - 1) * NTOK + tok) * DD;

  float* orow = out + (size_t)tok * DD;
#pragma unroll
  for (int j = 0; j < 4; j++) {
    const int d0 = lane * 8 + j * 512;
    bf16x8 bsv[4];
#pragma unroll
    for (int k = 0; k < 4; k++) bsv[k] = *(const bf16x8*)(bases[k] + d0);
    f32x4 o0, o1;
#pragma unroll
    for (int q = 0; q < 8; q++) {
      float s = bsum * bf2f(h2r[j][q]);
#pragma unroll
      for (int k = 0; k < 4; k++) s += e[k] * bf2f(bsv[k][q]);
      if (q < 4) o0[q] = s; else o1[q - 4] = s;
    }
    *(f32x4*)(orow + d0) = o0;
    *(f32x4*)(orow + d0 + 4) = o1;
  }
}

extern "C" void kernel_launch(void* const* d_in, const int* in_sizes, int n_in,
                              void* d_out, int out_size, void* d_ws,
                              size_t ws_size, hipStream_t stream) {
  const float* x = (const float*)d_in[0];
  const float* A_m = (const float*)d_in[1];
  const float* A_r = (const float*)d_in[2];
  const float* Bp = (const float*)d_in[3];
  const float* W_m = (const float*)d_in[4];
  const float* W_r = (const float*)d_in[5];
  const float* W_b = (const float*)d_in[6];
  const float* s_a = (const float*)d_in[7];
  const float* s_b = (const float*)d_in[8];
  const float* dyn_gamma = (const float*)d_in[9];
  const float* norm_gamma = (const float*)d_in[10];
  const float* norm_beta = (const float*)d_in[11];
  const float* Wblk = (const float*)d_in[12];
  const float* bblk = (const float*)d_in[13];
  float* out = (float*)d_out;

  char* ws = (char*)d_ws;
  short* b0 = (short*)(ws);                    // 16 MiB: bf16 copy of x
  short* h2s = (short*)(ws + 16777216);        // 4 slots x 16 MiB
  short* hnorm = (short*)(ws + 83886080);      // 16 MiB
  char* aux = ws + 100663296;
  short* gwm = (short*)(aux);                  // 16 KiB
  short* gwr = (short*)(aux + 16384);          // 64 KiB
  short* gwb = (short*)(aux + 81920);          // 64 KiB
  float* rb = (float*)(aux + 147456);          // 32 KiB
  float* S0w = (float*)(aux + 180224);
  float* T0d = (float*)(aux + 181248);
  f32x2* tst = (f32x2*)(aux + 182272);         // 32 KiB
  float* E0 = (float*)(aux + 215040);          // 32 KiB
  float* E1 = (float*)(aux + 247808);          // 32 KiB
  float* Cc = (float*)(aux + 280576);          // 256 KiB: C[tok][4][4]
  float* ST = (float*)(aux + 542720);          // 1.25 MiB: stats[tok][80]
  short* Wt = (short*)d_out;  // recomputed every call, overwritten at end

  dim3 tb(256);
  prep_pack<<<32, tb, 0, stream>>>(W_m, W_r, W_b, dyn_gamma, norm_gamma,
                                   norm_beta, gwm, gwr, gwb, rb);
  prep_sums<<<4, dim3(64), 0, stream>>>(W_m, W_r, W_b, dyn_gamma, S0w, T0d);
  transpose_wblk<<<dim3(32, 32, 4), tb, 0, stream>>>(Wblk, norm_gamma, Wt);
  row_sums<<<dim3(512, 4), tb, 0, stream>>>(Wt, rb, bblk, E0, E1);
  width0_kernel<<<1024, tb, 0, stream>>>(x, b0, hnorm, tst, Cc, ST, A_m, A_r,
                                         gwm, gwr, s_a, S0w);
  for (int i = 0; i < LL; i++) {
    gemm_kernel<<<512, dim3(512), 0, stream>>>(
        hnorm, Wt + (size_t)i * DD * DD, tst, E0 + i * DD, E1 + i * DD,
        h2s + (size_t)i * NTOK * DD);
    if (i == 0)
      fused_dw<0><<<1024, tb, 0, stream>>>(h2s, b0, hnorm, tst, Cc, ST, Bp,
                                           s_b, A_m, A_r, s_a, S0w, T0d, gwm,
                                           gwr, gwb);
    else if (i == 1)
      fused_dw<1><<<1024, tb, 0, stream>>>(h2s, b0, hnorm, tst, Cc, ST, Bp,
                                           s_b, A_m, A_r, s_a, S0w, T0d, gwm,
                                           gwr, gwb);
    else if (i == 2)
      fused_dw<2><<<1024, tb, 0, stream>>>(h2s, b0, hnorm, tst, Cc, ST, Bp,
                                           s_b, A_m, A_r, s_a, S0w, T0d, gwm,
                                           gwr, gwb);
    else
      depth_last<<<1024, tb, 0, stream>>>(h2s, b0, out, Cc, Bp, s_b, T0d, gwb);
  }
}